// Round 3
// baseline (411.557 us; speedup 1.0000x reference)
//
#include <hip/hip_runtime.h>
#include <hip/hip_bf16.h>

typedef short bf16x8 __attribute__((ext_vector_type(8)));
typedef float f32x4  __attribute__((ext_vector_type(4)));

#define DIN  4096
#define DOUT 4096
#define MTOT 8192
#define RNK  32
#define NT   64   // K-tiles of BK=64

union Pk8 { __hip_bfloat16 h[8]; uint4 u; bf16x8 v; };

__device__ __forceinline__ uint4 pack8(float a0,float a1,float a2,float a3,
                                       float b0,float b1,float b2,float b3){
  Pk8 p;
  p.h[0]=__float2bfloat16(a0); p.h[1]=__float2bfloat16(a1);
  p.h[2]=__float2bfloat16(a2); p.h[3]=__float2bfloat16(a3);
  p.h[4]=__float2bfloat16(b0); p.h[5]=__float2bfloat16(b1);
  p.h[6]=__float2bfloat16(b2); p.h[7]=__float2bfloat16(b3);
  return p.u;
}
__device__ __forceinline__ bf16x8 pack8v(float a0,float a1,float a2,float a3,
                                         float b0,float b1,float b2,float b3){
  Pk8 p;
  p.h[0]=__float2bfloat16(a0); p.h[1]=__float2bfloat16(a1);
  p.h[2]=__float2bfloat16(a2); p.h[3]=__float2bfloat16(a3);
  p.h[4]=__float2bfloat16(b0); p.h[5]=__float2bfloat16(b1);
  p.h[6]=__float2bfloat16(b2); p.h[7]=__float2bfloat16(b3);
  return p.v;
}

__device__ __forceinline__ void gload_lds16(const void* g, void* l){
  __builtin_amdgcn_global_load_lds(
      (const __attribute__((address_space(1))) unsigned int*)g,
      (__attribute__((address_space(3))) unsigned int*)l, 16, 0, 0);
}

#define MFMA(A,B,C) __builtin_amdgcn_mfma_f32_16x16x32_bf16(A,B,C,0,0,0)
#define BAR   asm volatile("s_barrier" ::: "memory")
#define PRIO1 __builtin_amdgcn_s_setprio(1)
#define PRIO0 __builtin_amdgcn_s_setprio(0)

// ---------------- prep: W fp32 -> bf16 ----------------
__global__ __launch_bounds__(256) void k_conv_w(const float* __restrict__ W,
                                                __hip_bfloat16* __restrict__ Wb){
  size_t i = ((size_t)blockIdx.x*256 + threadIdx.x) * 8;
  float4 a = *(const float4*)(W + i);
  float4 b = *(const float4*)(W + i + 4);
  *(uint4*)(Wb + i) = pack8(a.x,a.y,a.z,a.w,b.x,b.y,b.z,b.w);
}

// ---------------- prep: A -> At[32][4096] bf16 ; B -> Bt[4096][32] bf16 ----
__global__ __launch_bounds__(256) void k_conv_ab(const float* __restrict__ A,
                                                 const float* __restrict__ B,
                                                 __hip_bfloat16* __restrict__ At,
                                                 __hip_bfloat16* __restrict__ Bt){
  int idx = blockIdx.x*256 + threadIdx.x;
  if (idx < DIN*RNK){
    int k = idx >> 5, r = idx & 31;
    At[(size_t)r*DIN + k] = __float2bfloat16(A[(size_t)k*RNK + r]);
  } else {
    int j = idx - DIN*RNK;
    int n = j >> 5, k = j & 31;
    Bt[(size_t)n*RNK + k] = __float2bfloat16(B[(size_t)k*DOUT + n]);
  }
}

// ---------------- fused: x -> x_bf16 ; t = (x*mask) @ A  ------------------
// Barrier-free main loop: 512 blocks x 256 thr; block owns 16 rows; each of
// 4 waves owns a K-quarter (1024) and accumulates t-partials in registers
// (frags loaded straight from global in MFMA layout). One LDS reduce at end.
__global__ __launch_bounds__(256) void k_xt(const float* __restrict__ x,
                                            const float* __restrict__ mk,
                                            const __hip_bfloat16* __restrict__ At,
                                            __hip_bfloat16* __restrict__ xb,
                                            __hip_bfloat16* __restrict__ tb){
  __shared__ float sred[4*512];   // 8 KB
  const int t = threadIdx.x, w = t >> 6, l = t & 63;
  const int r0 = blockIdx.x * 16;
  const int lane15 = l & 15, kb = l >> 4;
  const size_t rowbase = (size_t)(r0 + lane15) * DIN;
  const int kbase = w * 1024;

  f32x4 acc0 = {0.f,0.f,0.f,0.f}, acc1 = {0.f,0.f,0.f,0.f};
  const __hip_bfloat16* at0 = At + (size_t)lane15*DIN;
  const __hip_bfloat16* at1 = At + (size_t)(16+lane15)*DIN;

  #pragma unroll 2
  for (int kt = 0; kt < 32; ++kt){
    const int k0 = kbase + kt*32 + kb*8;
    float4 xa = *(const float4*)(x  + rowbase + k0);
    float4 xc = *(const float4*)(x  + rowbase + k0 + 4);
    float4 ma = *(const float4*)(mk + rowbase + k0);
    float4 mc = *(const float4*)(mk + rowbase + k0 + 4);
    *(uint4*)(xb + rowbase + k0) = pack8(xa.x,xa.y,xa.z,xa.w,xc.x,xc.y,xc.z,xc.w);
    bf16x8 af = pack8v(xa.x*ma.x,xa.y*ma.y,xa.z*ma.z,xa.w*ma.w,
                       xc.x*mc.x,xc.y*mc.y,xc.z*mc.z,xc.w*mc.w);
    bf16x8 b0 = *(const bf16x8*)(at0 + k0);
    bf16x8 b1 = *(const bf16x8*)(at1 + k0);
    acc0 = MFMA(af, b0, acc0);
    acc1 = MFMA(af, b1, acc1);
  }

  #pragma unroll
  for (int r = 0; r < 4; ++r){
    sred[(w*64+l)*8 + r]     = acc0[r];
    sred[(w*64+l)*8 + 4 + r] = acc1[r];
  }
  __syncthreads();
  #pragma unroll
  for (int e2 = 0; e2 < 2; ++e2){
    int e  = t*2 + e2;              // e = el*8 + er
    int el = e >> 3, er = e & 7;
    float s = sred[el*8+er] + sred[512+el*8+er] + sred[1024+el*8+er] + sred[1536+el*8+er];
    int col  = (er>>2)*16 + (el & 15);
    int orow = (el>>4)*4 + (er & 3);
    tb[(size_t)(r0 + orow)*RNK + col] = __float2bfloat16(s);
  }
}

// ---------------- main GEMM: 256x256 tile, BK=64, 8 waves, 4-phase counted-vmcnt
// LDS layout per buffer b: [A|B] x [khalf] x [256 rows][32 cols] bf16 (16KB segs)
// chunk swizzle: 16B-chunk col c stored at c ^ ((row>>1)&3)
// XCD map: xcd owns 2 n-cols x all 32 m-tiles -> concurrent wgs share one Wb panel
__global__ __launch_bounds__(512, 2) void k_main2(const __hip_bfloat16* __restrict__ xb,
                                                  const __hip_bfloat16* __restrict__ Wb,
                                                  const __hip_bfloat16* __restrict__ tb,
                                                  const __hip_bfloat16* __restrict__ Bt,
                                                  float* __restrict__ out){
  __shared__ __align__(16) __hip_bfloat16 lds[65536];   // 128 KiB
  const int tid = threadIdx.x;
  const int l  = tid & 63, w = tid >> 6;
  const int wm = w >> 2,  wn = w & 3;       // 2x4 wave grid; wave tile 128x64
  const int lr = l & 15;
  const int ch = ((l >> 4) ^ ((l >> 1) & 3)) & 3;       // swizzled 16B-chunk per lane
  const int laneA = (wm*128 + lr)*32 + ch*8;            // elements within a 16KB seg
  const int laneB = (wn*64  + lr)*32 + ch*8;
  const int g_row = tid >> 2;                           // staging: row within 128-row half
  const int g_ch  = (((tid & 3) ^ ((tid >> 3) & 3))) * 8;

  const int bid  = blockIdx.x;
  const int xcd  = bid & 7, chunk = bid >> 3;           // chunk 0..63
  const int bm0  = (chunk & 31) * 256;                  // m fastest within XCD
  const int bn0  = (xcd*2 + (chunk >> 5)) * 256;        // XCD owns 2 n-columns

  f32x4 acc[8][4];

  // ---- LoRA prologue: acc = t_frag @ Bt_frag (K=32), initializes acc ----
  {
    const __hip_bfloat16* tp = tb + (size_t)(bm0 + wm*128 + lr)*RNK + (l>>4)*8;
    const __hip_bfloat16* bp = Bt + (size_t)(bn0 + wn*64  + lr)*RNK + (l>>4)*8;
    bf16x8 tf[8], bf[4];
    #pragma unroll
    for (int m = 0; m < 8; ++m) tf[m] = *(const bf16x8*)(tp + m*16*RNK);
    #pragma unroll
    for (int n = 0; n < 4; ++n) bf[n] = *(const bf16x8*)(bp + n*16*RNK);
    const f32x4 z = {0.f,0.f,0.f,0.f};
    #pragma unroll
    for (int m = 0; m < 8; ++m)
      #pragma unroll
      for (int n = 0; n < 4; ++n)
        acc[m][n] = MFMA(tf[m], bf[n], z);
  }
  asm volatile("" ::: "memory");

  // stage one 16KB region (tile kt, ab: 0=A(xb) 1=B(Wb), khalf kh) into buffer bb
  auto STAGE = [&](int bb, int ab, int kh, int kt){
    const __hip_bfloat16* g = ab ? Wb : xb;
    const int base0 = ab ? bn0 : bm0;
    const int segb  = bb*32768 + ab*16384 + kh*8192;    // elements
    #pragma unroll
    for (int i = 0; i < 2; ++i){
      const __hip_bfloat16* src = g + (size_t)(base0 + i*128 + g_row)*DIN
                                    + kt*64 + kh*32 + g_ch;
      gload_lds16(src, (void*)&lds[segb + i*4096 + w*512]);
    }
  };

  // prologue: tile0 fully, tile1 except A-k1 (A-k1(1) staged at P0 of iter 0)
  STAGE(0,1,0,0); STAGE(0,0,0,0); STAGE(0,1,1,0); STAGE(0,0,1,0);
  STAGE(1,1,0,1); STAGE(1,0,0,1); STAGE(1,1,1,1);
  asm volatile("s_waitcnt vmcnt(6)" ::: "memory");      // tile0 resident
  BAR;

  #define LDV(off) (*(const bf16x8*)&lds[(off)])

  for (int t = 0; t < NT; ++t){
    const int b   = t & 1;
    const int sA0 = b*32768;
    const int sA1 = b*32768 + 8192;
    const int sB0 = b*32768 + 16384;
    const int sB1 = b*32768 + 24576;
    bf16x8 bk0[4], bk1[4];
    bf16x8 a0, a1, a2, a3;

    // ---- P0: reads A-k0 m0-3 + B-k0 (8); stage A-k1(t+1)->buf b^1; MFMA k0,m0-3
    a0 = LDV(sA0+laneA);        a1 = LDV(sA0+laneA+512);
    a2 = LDV(sA0+laneA+1024);   a3 = LDV(sA0+laneA+1536);
    #pragma unroll
    for (int n = 0; n < 4; ++n) bk0[n] = LDV(sB0+laneB+n*512);
    if (t+1 < NT) STAGE(b^1, 0, 1, t+1);
    BAR;
    PRIO1;
    #pragma unroll
    for (int n = 0; n < 4; ++n){
      acc[0][n] = MFMA(a0, bk0[n], acc[0][n]);
      acc[1][n] = MFMA(a1, bk0[n], acc[1][n]);
      acc[2][n] = MFMA(a2, bk0[n], acc[2][n]);
      acc[3][n] = MFMA(a3, bk0[n], acc[3][n]);
    }
    PRIO0;
    BAR;

    // ---- P1: reads A-k0 m4-7 + B-k1 (8); stage B-k0(t+2)->buf b; MFMA k0,m4-7
    a0 = LDV(sA0+laneA+2048);   a1 = LDV(sA0+laneA+2560);
    a2 = LDV(sA0+laneA+3072);   a3 = LDV(sA0+laneA+3584);
    #pragma unroll
    for (int n = 0; n < 4; ++n) bk1[n] = LDV(sB1+laneB+n*512);
    if (t+2 < NT) STAGE(b, 1, 0, t+2);
    BAR;
    PRIO1;
    #pragma unroll
    for (int n = 0; n < 4; ++n){
      acc[4][n] = MFMA(a0, bk0[n], acc[4][n]);
      acc[5][n] = MFMA(a1, bk0[n], acc[5][n]);
      acc[6][n] = MFMA(a2, bk0[n], acc[6][n]);
      acc[7][n] = MFMA(a3, bk0[n], acc[7][n]);
    }
    PRIO0;
    BAR;

    // ---- P2: reads A-k1 m0-3 (4); stage A-k0(t+2)->buf b; MFMA k1,m0-3
    a0 = LDV(sA1+laneA);        a1 = LDV(sA1+laneA+512);
    a2 = LDV(sA1+laneA+1024);   a3 = LDV(sA1+laneA+1536);
    if (t+2 < NT) STAGE(b, 0, 0, t+2);
    BAR;
    PRIO1;
    #pragma unroll
    for (int n = 0; n < 4; ++n){
      acc[0][n] = MFMA(a0, bk1[n], acc[0][n]);
      acc[1][n] = MFMA(a1, bk1[n], acc[1][n]);
      acc[2][n] = MFMA(a2, bk1[n], acc[2][n]);
      acc[3][n] = MFMA(a3, bk1[n], acc[3][n]);
    }
    PRIO0;
    BAR;

    // ---- P3: reads A-k1 m4-7 (4); stage B-k1(t+2)->buf b; MFMA k1,m4-7; vmcnt
    a0 = LDV(sA1+laneA+2048);   a1 = LDV(sA1+laneA+2560);
    a2 = LDV(sA1+laneA+3072);   a3 = LDV(sA1+laneA+3584);
    if (t+2 < NT) STAGE(b, 1, 1, t+2);
    BAR;
    PRIO1;
    #pragma unroll
    for (int n = 0; n < 4; ++n){
      acc[4][n] = MFMA(a0, bk1[n], acc[4][n]);
      acc[5][n] = MFMA(a1, bk1[n], acc[5][n]);
      acc[6][n] = MFMA(a2, bk1[n], acc[6][n]);
      acc[7][n] = MFMA(a3, bk1[n], acc[7][n]);
    }
    PRIO0;
    if (t < NT-2)       asm volatile("s_waitcnt vmcnt(6)" ::: "memory");
    else if (t == NT-2) asm volatile("s_waitcnt vmcnt(0)" ::: "memory");
    BAR;
  }

  // ---- epilogue: C write (f32) ----
  const int orow = bm0 + wm*128 + (l>>4)*4;
  const int ocol = bn0 + wn*64  + (l&15);
  #pragma unroll
  for (int m = 0; m < 8; ++m)
    #pragma unroll
    for (int n = 0; n < 4; ++n)
      #pragma unroll
      for (int r = 0; r < 4; ++r)
        out[(size_t)(orow + m*16 + r)*DOUT + ocol + n*16] = acc[m][n][r];
  #undef LDV
}

// ---------------- fallback (ws too small): slow but correct fp32 ----------
__global__ void fb_t(const float* __restrict__ x, const float* __restrict__ mk,
                     const float* __restrict__ A, float* __restrict__ tf){
  const int m = blockIdx.x, t = threadIdx.x;
  float acc[RNK];
  #pragma unroll
  for (int r = 0; r < RNK; ++r) acc[r] = 0.f;
  for (int k = t; k < DIN; k += 256){
    float xm = x[(size_t)m*DIN + k] * mk[(size_t)m*DIN + k];
    #pragma unroll
    for (int r = 0; r < RNK; ++r) acc[r] += xm * A[(size_t)k*RNK + r];
  }
  #pragma unroll
  for (int r = 0; r < RNK; ++r){
    float v = acc[r];
    for (int o = 32; o; o >>= 1) v += __shfl_down(v, o);
    if ((t & 63) == 0) atomicAdd(&tf[(size_t)m*RNK + r], v);
  }
}

__global__ void fb_out(const float* __restrict__ x, const float* __restrict__ W,
                       const float* __restrict__ B, const float* __restrict__ tf,
                       float* __restrict__ out){
  size_t idx = (size_t)blockIdx.x*256 + threadIdx.x;
  int m = (int)(idx >> 12), n = (int)(idx & 4095);
  float acc = 0.f;
  for (int k = 0; k < DIN; ++k)
    acc += x[(size_t)m*DIN + k] * W[(size_t)n*DIN + k];
  #pragma unroll
  for (int r = 0; r < RNK; ++r)
    acc += tf[(size_t)m*RNK + r] * B[(size_t)r*DOUT + n];
  out[idx] = acc;
}

extern "C" void kernel_launch(void* const* d_in, const int* in_sizes, int n_in,
                              void* d_out, int out_size, void* d_ws, size_t ws_size,
                              hipStream_t stream) {
  const float* x  = (const float*)d_in[0];
  const float* W  = (const float*)d_in[1];
  const float* A  = (const float*)d_in[2];
  const float* B  = (const float*)d_in[3];
  const float* mk = (const float*)d_in[4];
  float* out = (float*)d_out;

  const size_t OFF_XB = 0;
  const size_t OFF_WB = OFF_XB + (size_t)MTOT*DIN*2;
  const size_t OFF_TB = OFF_WB + (size_t)DOUT*DIN*2;
  const size_t OFF_AT = OFF_TB + (size_t)MTOT*RNK*2;
  const size_t OFF_BT = OFF_AT + (size_t)RNK*DIN*2;
  const size_t NEED   = OFF_BT + (size_t)DIN*RNK*2;

  if (ws_size >= NEED){
    char* ws = (char*)d_ws;
    __hip_bfloat16* xb = (__hip_bfloat16*)(ws + OFF_XB);
    __hip_bfloat16* Wb = (__hip_bfloat16*)(ws + OFF_WB);
    __hip_bfloat16* tb = (__hip_bfloat16*)(ws + OFF_TB);
    __hip_bfloat16* At = (__hip_bfloat16*)(ws + OFF_AT);
    __hip_bfloat16* Bt = (__hip_bfloat16*)(ws + OFF_BT);

    k_conv_w <<<(DOUT*(size_t)DIN)/(256*8), 256, 0, stream>>>(W, Wb);
    k_conv_ab<<<(2*DIN*RNK)/256,            256, 0, stream>>>(A, B, At, Bt);
    k_xt     <<<MTOT/16,                    256, 0, stream>>>(x, mk, At, xb, tb);
    k_main2  <<<(MTOT/256)*(DOUT/256),      512, 0, stream>>>(xb, Wb, tb, Bt, out);
  } else {
    float* tf = (float*)d_ws;
    hipMemsetAsync(tf, 0, (size_t)MTOT*RNK*4, stream);
    fb_t  <<<MTOT, 256, 0, stream>>>(x, mk, A, tf);
    fb_out<<<((size_t)MTOT*DOUT)/256, 256, 0, stream>>>(x, W, B, tf, out);
  }
}

// Round 4
// 337.716 us; speedup vs baseline: 1.2186x; 1.2186x over previous
//
#include <hip/hip_runtime.h>
#include <hip/hip_bf16.h>

typedef short bf16x8 __attribute__((ext_vector_type(8)));
typedef float f32x4  __attribute__((ext_vector_type(4)));

#define DIN  4096
#define DOUT 4096
#define MTOT 8192
#define RNK  32
#define NT   64   // K-tiles of BK=64

union Pk8 { __hip_bfloat16 h[8]; uint4 u; bf16x8 v; };

__device__ __forceinline__ uint4 pack8(float a0,float a1,float a2,float a3,
                                       float b0,float b1,float b2,float b3){
  Pk8 p;
  p.h[0]=__float2bfloat16(a0); p.h[1]=__float2bfloat16(a1);
  p.h[2]=__float2bfloat16(a2); p.h[3]=__float2bfloat16(a3);
  p.h[4]=__float2bfloat16(b0); p.h[5]=__float2bfloat16(b1);
  p.h[6]=__float2bfloat16(b2); p.h[7]=__float2bfloat16(b3);
  return p.u;
}
__device__ __forceinline__ bf16x8 pack8v(float a0,float a1,float a2,float a3,
                                         float b0,float b1,float b2,float b3){
  Pk8 p;
  p.h[0]=__float2bfloat16(a0); p.h[1]=__float2bfloat16(a1);
  p.h[2]=__float2bfloat16(a2); p.h[3]=__float2bfloat16(a3);
  p.h[4]=__float2bfloat16(b0); p.h[5]=__float2bfloat16(b1);
  p.h[6]=__float2bfloat16(b2); p.h[7]=__float2bfloat16(b3);
  return p.v;
}

__device__ __forceinline__ void gload_lds16(const void* g, void* l){
  __builtin_amdgcn_global_load_lds(
      (const __attribute__((address_space(1))) unsigned int*)g,
      (__attribute__((address_space(3))) unsigned int*)l, 16, 0, 0);
}

#define MFMA(A,B,C) __builtin_amdgcn_mfma_f32_16x16x32_bf16(A,B,C,0,0,0)
#define BAR   asm volatile("s_barrier" ::: "memory")
#define PRIO1 __builtin_amdgcn_s_setprio(1)
#define PRIO0 __builtin_amdgcn_s_setprio(0)

// ---------------- prep: W fp32 -> bf16 ----------------
__global__ __launch_bounds__(256) void k_conv_w(const float* __restrict__ W,
                                                __hip_bfloat16* __restrict__ Wb){
  size_t i = ((size_t)blockIdx.x*256 + threadIdx.x) * 8;
  float4 a = *(const float4*)(W + i);
  float4 b = *(const float4*)(W + i + 4);
  *(uint4*)(Wb + i) = pack8(a.x,a.y,a.z,a.w,b.x,b.y,b.z,b.w);
}

// ---------------- prep: A -> At[32][4096] bf16 ; B -> Bt[4096][32] bf16 ----
__global__ __launch_bounds__(256) void k_conv_ab(const float* __restrict__ A,
                                                 const float* __restrict__ B,
                                                 __hip_bfloat16* __restrict__ At,
                                                 __hip_bfloat16* __restrict__ Bt){
  int idx = blockIdx.x*256 + threadIdx.x;
  if (idx < DIN*RNK){
    int k = idx >> 5, r = idx & 31;
    At[(size_t)r*DIN + k] = __float2bfloat16(A[(size_t)k*RNK + r]);
  } else {
    int j = idx - DIN*RNK;
    int n = j >> 5, k = j & 31;
    Bt[(size_t)n*RNK + k] = __float2bfloat16(B[(size_t)k*DOUT + n]);
  }
}

// ---------------- fused: x -> x_bf16 ; t = (x*mask) @ A  ------------------
// Barrier-free main loop: 512 blocks x 256 thr; block owns 16 rows; each of
// 4 waves owns a K-quarter (1024) and accumulates t-partials in registers
// (frags loaded straight from global in MFMA layout). One LDS reduce at end.
__global__ __launch_bounds__(256) void k_xt(const float* __restrict__ x,
                                            const float* __restrict__ mk,
                                            const __hip_bfloat16* __restrict__ At,
                                            __hip_bfloat16* __restrict__ xb,
                                            __hip_bfloat16* __restrict__ tb){
  __shared__ float sred[4*512];   // 8 KB
  const int t = threadIdx.x, w = t >> 6, l = t & 63;
  const int r0 = blockIdx.x * 16;
  const int lane15 = l & 15, kb = l >> 4;
  const size_t rowbase = (size_t)(r0 + lane15) * DIN;
  const int kbase = w * 1024;

  f32x4 acc0 = {0.f,0.f,0.f,0.f}, acc1 = {0.f,0.f,0.f,0.f};
  const __hip_bfloat16* at0 = At + (size_t)lane15*DIN;
  const __hip_bfloat16* at1 = At + (size_t)(16+lane15)*DIN;

  #pragma unroll 2
  for (int kt = 0; kt < 32; ++kt){
    const int k0 = kbase + kt*32 + kb*8;
    float4 xa = *(const float4*)(x  + rowbase + k0);
    float4 xc = *(const float4*)(x  + rowbase + k0 + 4);
    float4 ma = *(const float4*)(mk + rowbase + k0);
    float4 mc = *(const float4*)(mk + rowbase + k0 + 4);
    *(uint4*)(xb + rowbase + k0) = pack8(xa.x,xa.y,xa.z,xa.w,xc.x,xc.y,xc.z,xc.w);
    bf16x8 af = pack8v(xa.x*ma.x,xa.y*ma.y,xa.z*ma.z,xa.w*ma.w,
                       xc.x*mc.x,xc.y*mc.y,xc.z*mc.z,xc.w*mc.w);
    bf16x8 b0 = *(const bf16x8*)(at0 + k0);
    bf16x8 b1 = *(const bf16x8*)(at1 + k0);
    acc0 = MFMA(af, b0, acc0);
    acc1 = MFMA(af, b1, acc1);
  }

  #pragma unroll
  for (int r = 0; r < 4; ++r){
    sred[(w*64+l)*8 + r]     = acc0[r];
    sred[(w*64+l)*8 + 4 + r] = acc1[r];
  }
  __syncthreads();
  #pragma unroll
  for (int e2 = 0; e2 < 2; ++e2){
    int e  = t*2 + e2;              // e = el*8 + er
    int el = e >> 3, er = e & 7;
    float s = sred[el*8+er] + sred[512+el*8+er] + sred[1024+el*8+er] + sred[1536+el*8+er];
    int col  = (er>>2)*16 + (el & 15);
    int orow = (el>>4)*4 + (er & 3);
    tb[(size_t)(r0 + orow)*RNK + col] = __float2bfloat16(s);
  }
}

// ---------------- main GEMM: 256x256 tile, BK=64, 8 waves, 4-phase counted-vmcnt
// LDS layout per buffer b: [A|B] x [khalf] x [256 rows][32 cols] bf16 (16KB segs)
// chunk swizzle: 16B-chunk col c stored at c ^ ((row>>1)&3)
// XCD map: 8 regions of 8m x 8n tiles -> per-XCD fetch = 16 panels = 32 MB
__global__ __launch_bounds__(512, 2) void k_main2(const __hip_bfloat16* __restrict__ xb,
                                                  const __hip_bfloat16* __restrict__ Wb,
                                                  const __hip_bfloat16* __restrict__ tb,
                                                  const __hip_bfloat16* __restrict__ Bt,
                                                  float* __restrict__ out){
  __shared__ __align__(16) __hip_bfloat16 lds[65536];   // 128 KiB
  const int tid = threadIdx.x;
  const int l  = tid & 63, w = tid >> 6;
  const int wm = w >> 2,  wn = w & 3;       // 2x4 wave grid; wave tile 128x64
  const int lr = l & 15;
  const int ch = ((l >> 4) ^ ((l >> 1) & 3)) & 3;       // swizzled 16B-chunk per lane
  const int laneA = (wm*128 + lr)*32 + ch*8;            // elements within a 16KB seg
  const int laneB = (wn*64  + lr)*32 + ch*8;
  const int g_row = tid >> 2;                           // staging: row within 128-row half
  const int g_ch  = (((tid & 3) ^ ((tid >> 3) & 3))) * 8;

  // 8 XCD regions of 8m x 8n (tile grid 32m x 16n); bijective
  const int bid  = blockIdx.x;
  const int xcd  = bid & 7;
  const int idx  = bid >> 3;                            // 0..63
  const int bm0  = (((xcd >> 1) << 3) + (idx & 7)) * 256;
  const int bn0  = (((xcd & 1) << 3) + (idx >> 3)) * 256;

  f32x4 acc[8][4];

  // ---- LoRA prologue: acc = t_frag @ Bt_frag (K=32), initializes acc ----
  {
    const __hip_bfloat16* tp = tb + (size_t)(bm0 + wm*128 + lr)*RNK + (l>>4)*8;
    const __hip_bfloat16* bp = Bt + (size_t)(bn0 + wn*64  + lr)*RNK + (l>>4)*8;
    bf16x8 tf[8], bf[4];
    #pragma unroll
    for (int m = 0; m < 8; ++m) tf[m] = *(const bf16x8*)(tp + m*16*RNK);
    #pragma unroll
    for (int n = 0; n < 4; ++n) bf[n] = *(const bf16x8*)(bp + n*16*RNK);
    const f32x4 z = {0.f,0.f,0.f,0.f};
    #pragma unroll
    for (int m = 0; m < 8; ++m)
      #pragma unroll
      for (int n = 0; n < 4; ++n)
        acc[m][n] = MFMA(tf[m], bf[n], z);
  }
  asm volatile("" ::: "memory");

  // stage one 16KB region (tile kt, ab: 0=A(xb) 1=B(Wb), khalf kh) into buffer bb
  auto STAGE = [&](int bb, int ab, int kh, int kt){
    const __hip_bfloat16* g = ab ? Wb : xb;
    const int base0 = ab ? bn0 : bm0;
    const int segb  = bb*32768 + ab*16384 + kh*8192;    // elements
    #pragma unroll
    for (int i = 0; i < 2; ++i){
      const __hip_bfloat16* src = g + (size_t)(base0 + i*128 + g_row)*DIN
                                    + kt*64 + kh*32 + g_ch;
      gload_lds16(src, (void*)&lds[segb + i*4096 + w*512]);
    }
  };

  // prologue: tile0 fully, tile1 except A-k1 (A-k1(1) staged at P0 of iter 0)
  STAGE(0,1,0,0); STAGE(0,0,0,0); STAGE(0,1,1,0); STAGE(0,0,1,0);
  STAGE(1,1,0,1); STAGE(1,0,0,1); STAGE(1,1,1,1);
  asm volatile("s_waitcnt vmcnt(6)" ::: "memory");      // tile0 resident
  BAR;

  #define LDV(off) (*(const bf16x8*)&lds[(off)])

  for (int t = 0; t < NT; ++t){
    const int b   = t & 1;
    const int sA0 = b*32768;
    const int sA1 = b*32768 + 8192;
    const int sB0 = b*32768 + 16384;
    const int sB1 = b*32768 + 24576;
    bf16x8 bk0[4], bk1[4];
    bf16x8 a0, a1, a2, a3;

    // ---- P0: reads A-k0 m0-3 + B-k0 (8); stage A-k1(t+1)->buf b^1; MFMA k0,m0-3
    a0 = LDV(sA0+laneA);        a1 = LDV(sA0+laneA+512);
    a2 = LDV(sA0+laneA+1024);   a3 = LDV(sA0+laneA+1536);
    #pragma unroll
    for (int n = 0; n < 4; ++n) bk0[n] = LDV(sB0+laneB+n*512);
    if (t+1 < NT) STAGE(b^1, 0, 1, t+1);
    BAR;
    PRIO1;
    #pragma unroll
    for (int n = 0; n < 4; ++n){
      acc[0][n] = MFMA(a0, bk0[n], acc[0][n]);
      acc[1][n] = MFMA(a1, bk0[n], acc[1][n]);
      acc[2][n] = MFMA(a2, bk0[n], acc[2][n]);
      acc[3][n] = MFMA(a3, bk0[n], acc[3][n]);
    }
    PRIO0;
    BAR;

    // ---- P1: reads A-k0 m4-7 + B-k1 (8); stage B-k0(t+2)->buf b; MFMA k0,m4-7
    a0 = LDV(sA0+laneA+2048);   a1 = LDV(sA0+laneA+2560);
    a2 = LDV(sA0+laneA+3072);   a3 = LDV(sA0+laneA+3584);
    #pragma unroll
    for (int n = 0; n < 4; ++n) bk1[n] = LDV(sB1+laneB+n*512);
    if (t+2 < NT) STAGE(b, 1, 0, t+2);
    BAR;
    PRIO1;
    #pragma unroll
    for (int n = 0; n < 4; ++n){
      acc[4][n] = MFMA(a0, bk0[n], acc[4][n]);
      acc[5][n] = MFMA(a1, bk0[n], acc[5][n]);
      acc[6][n] = MFMA(a2, bk0[n], acc[6][n]);
      acc[7][n] = MFMA(a3, bk0[n], acc[7][n]);
    }
    PRIO0;
    BAR;

    // ---- P2: reads A-k1 m0-3 (4); stage A-k0(t+2)->buf b; MFMA k1,m0-3
    a0 = LDV(sA1+laneA);        a1 = LDV(sA1+laneA+512);
    a2 = LDV(sA1+laneA+1024);   a3 = LDV(sA1+laneA+1536);
    if (t+2 < NT) STAGE(b, 0, 0, t+2);
    BAR;
    PRIO1;
    #pragma unroll
    for (int n = 0; n < 4; ++n){
      acc[0][n] = MFMA(a0, bk1[n], acc[0][n]);
      acc[1][n] = MFMA(a1, bk1[n], acc[1][n]);
      acc[2][n] = MFMA(a2, bk1[n], acc[2][n]);
      acc[3][n] = MFMA(a3, bk1[n], acc[3][n]);
    }
    PRIO0;
    BAR;

    // ---- P3: reads A-k1 m4-7 (4); stage B-k1(t+2)->buf b; MFMA k1,m4-7; vmcnt
    a0 = LDV(sA1+laneA+2048);   a1 = LDV(sA1+laneA+2560);
    a2 = LDV(sA1+laneA+3072);   a3 = LDV(sA1+laneA+3584);
    if (t+2 < NT) STAGE(b, 1, 1, t+2);
    BAR;
    PRIO1;
    #pragma unroll
    for (int n = 0; n < 4; ++n){
      acc[4][n] = MFMA(a0, bk1[n], acc[4][n]);
      acc[5][n] = MFMA(a1, bk1[n], acc[5][n]);
      acc[6][n] = MFMA(a2, bk1[n], acc[6][n]);
      acc[7][n] = MFMA(a3, bk1[n], acc[7][n]);
    }
    PRIO0;
    if (t < NT-2)       asm volatile("s_waitcnt vmcnt(6)" ::: "memory");
    else if (t == NT-2) asm volatile("s_waitcnt vmcnt(0)" ::: "memory");
    BAR;
  }

  // ---- epilogue: C write (f32) ----
  const int orow = bm0 + wm*128 + (l>>4)*4;
  const int ocol = bn0 + wn*64  + (l&15);
  #pragma unroll
  for (int m = 0; m < 8; ++m)
    #pragma unroll
    for (int n = 0; n < 4; ++n)
      #pragma unroll
      for (int r = 0; r < 4; ++r)
        out[(size_t)(orow + m*16 + r)*DOUT + ocol + n*16] = acc[m][n][r];
  #undef LDV
}

// ---------------- fallback (ws too small): slow but correct fp32 ----------
__global__ void fb_t(const float* __restrict__ x, const float* __restrict__ mk,
                     const float* __restrict__ A, float* __restrict__ tf){
  const int m = blockIdx.x, t = threadIdx.x;
  float acc[RNK];
  #pragma unroll
  for (int r = 0; r < RNK; ++r) acc[r] = 0.f;
  for (int k = t; k < DIN; k += 256){
    float xm = x[(size_t)m*DIN + k] * mk[(size_t)m*DIN + k];
    #pragma unroll
    for (int r = 0; r < RNK; ++r) acc[r] += xm * A[(size_t)k*RNK + r];
  }
  #pragma unroll
  for (int r = 0; r < RNK; ++r){
    float v = acc[r];
    for (int o = 32; o; o >>= 1) v += __shfl_down(v, o);
    if ((t & 63) == 0) atomicAdd(&tf[(size_t)m*RNK + r], v);
  }
}

__global__ void fb_out(const float* __restrict__ x, const float* __restrict__ W,
                       const float* __restrict__ B, const float* __restrict__ tf,
                       float* __restrict__ out){
  size_t idx = (size_t)blockIdx.x*256 + threadIdx.x;
  int m = (int)(idx >> 12), n = (int)(idx & 4095);
  float acc = 0.f;
  for (int k = 0; k < DIN; ++k)
    acc += x[(size_t)m*DIN + k] * W[(size_t)n*DIN + k];
  #pragma unroll
  for (int r = 0; r < RNK; ++r)
    acc += tf[(size_t)m*RNK + r] * B[(size_t)r*DOUT + n];
  out[idx] = acc;
}

extern "C" void kernel_launch(void* const* d_in, const int* in_sizes, int n_in,
                              void* d_out, int out_size, void* d_ws, size_t ws_size,
                              hipStream_t stream) {
  const float* x  = (const float*)d_in[0];
  const float* W  = (const float*)d_in[1];
  const float* A  = (const float*)d_in[2];
  const float* B  = (const float*)d_in[3];
  const float* mk = (const float*)d_in[4];
  float* out = (float*)d_out;

  const size_t OFF_XB = 0;
  const size_t OFF_WB = OFF_XB + (size_t)MTOT*DIN*2;
  const size_t OFF_TB = OFF_WB + (size_t)DOUT*DIN*2;
  const size_t OFF_AT = OFF_TB + (size_t)MTOT*RNK*2;
  const size_t OFF_BT = OFF_AT + (size_t)RNK*DIN*2;
  const size_t NEED   = OFF_BT + (size_t)DIN*RNK*2;

  if (ws_size >= NEED){
    char* ws = (char*)d_ws;
    __hip_bfloat16* xb = (__hip_bfloat16*)(ws + OFF_XB);
    __hip_bfloat16* Wb = (__hip_bfloat16*)(ws + OFF_WB);
    __hip_bfloat16* tb = (__hip_bfloat16*)(ws + OFF_TB);
    __hip_bfloat16* At = (__hip_bfloat16*)(ws + OFF_AT);
    __hip_bfloat16* Bt = (__hip_bfloat16*)(ws + OFF_BT);

    k_conv_w <<<(DOUT*(size_t)DIN)/(256*8), 256, 0, stream>>>(W, Wb);
    k_conv_ab<<<(2*DIN*RNK)/256,            256, 0, stream>>>(A, B, At, Bt);
    k_xt     <<<MTOT/16,                    256, 0, stream>>>(x, mk, At, xb, tb);
    k_main2  <<<(MTOT/256)*(DOUT/256),      512, 0, stream>>>(xb, Wb, tb, Bt, out);
  } else {
    float* tf = (float*)d_ws;
    hipMemsetAsync(tf, 0, (size_t)MTOT*RNK*4, stream);
    fb_t  <<<MTOT, 256, 0, stream>>>(x, mk, A, tf);
    fb_out<<<((size_t)MTOT*DOUT)/256, 256, 0, stream>>>(x, W, B, tf, out);
  }
}

// Round 5
// 337.223 us; speedup vs baseline: 1.2204x; 1.0015x over previous
//
#include <hip/hip_runtime.h>
#include <hip/hip_bf16.h>

typedef short bf16x8 __attribute__((ext_vector_type(8)));
typedef float f32x4  __attribute__((ext_vector_type(4)));

#define DIN  4096
#define DOUT 4096
#define MTOT 8192
#define RNK  32
#define NT   64   // K-tiles of BK=64

union Pk8 { __hip_bfloat16 h[8]; uint4 u; bf16x8 v; };

__device__ __forceinline__ uint4 pack8(float a0,float a1,float a2,float a3,
                                       float b0,float b1,float b2,float b3){
  Pk8 p;
  p.h[0]=__float2bfloat16(a0); p.h[1]=__float2bfloat16(a1);
  p.h[2]=__float2bfloat16(a2); p.h[3]=__float2bfloat16(a3);
  p.h[4]=__float2bfloat16(b0); p.h[5]=__float2bfloat16(b1);
  p.h[6]=__float2bfloat16(b2); p.h[7]=__float2bfloat16(b3);
  return p.u;
}
__device__ __forceinline__ bf16x8 pack8v(float a0,float a1,float a2,float a3,
                                         float b0,float b1,float b2,float b3){
  Pk8 p;
  p.h[0]=__float2bfloat16(a0); p.h[1]=__float2bfloat16(a1);
  p.h[2]=__float2bfloat16(a2); p.h[3]=__float2bfloat16(a3);
  p.h[4]=__float2bfloat16(b0); p.h[5]=__float2bfloat16(b1);
  p.h[6]=__float2bfloat16(b2); p.h[7]=__float2bfloat16(b3);
  return p.v;
}

__device__ __forceinline__ void gload_lds16(const void* g, void* l){
  __builtin_amdgcn_global_load_lds(
      (const __attribute__((address_space(1))) unsigned int*)g,
      (__attribute__((address_space(3))) unsigned int*)l, 16, 0, 0);
}

#define MFMA(A,B,C) __builtin_amdgcn_mfma_f32_16x16x32_bf16(A,B,C,0,0,0)
#define BAR   asm volatile("s_barrier" ::: "memory")
#define SB0   __builtin_amdgcn_sched_barrier(0)
#define PRIO1 __builtin_amdgcn_s_setprio(1)
#define PRIO0 __builtin_amdgcn_s_setprio(0)

// ---------------- prep: W fp32 -> bf16 ----------------
__global__ __launch_bounds__(256) void k_conv_w(const float* __restrict__ W,
                                                __hip_bfloat16* __restrict__ Wb){
  size_t i = ((size_t)blockIdx.x*256 + threadIdx.x) * 8;
  float4 a = *(const float4*)(W + i);
  float4 b = *(const float4*)(W + i + 4);
  *(uint4*)(Wb + i) = pack8(a.x,a.y,a.z,a.w,b.x,b.y,b.z,b.w);
}

// ---------------- prep: A -> At[32][4096] bf16 ; B -> Bt[4096][32] bf16 ----
__global__ __launch_bounds__(256) void k_conv_ab(const float* __restrict__ A,
                                                 const float* __restrict__ B,
                                                 __hip_bfloat16* __restrict__ At,
                                                 __hip_bfloat16* __restrict__ Bt){
  int idx = blockIdx.x*256 + threadIdx.x;
  if (idx < DIN*RNK){
    int k = idx >> 5, r = idx & 31;
    At[(size_t)r*DIN + k] = __float2bfloat16(A[(size_t)k*RNK + r]);
  } else {
    int j = idx - DIN*RNK;
    int n = j >> 5, k = j & 31;
    Bt[(size_t)n*RNK + k] = __float2bfloat16(B[(size_t)k*DOUT + n]);
  }
}

// ---------------- fused: x -> x_bf16 ; t = (x*mask) @ A  ------------------
__global__ __launch_bounds__(256) void k_xt(const float* __restrict__ x,
                                            const float* __restrict__ mk,
                                            const __hip_bfloat16* __restrict__ At,
                                            __hip_bfloat16* __restrict__ xb,
                                            __hip_bfloat16* __restrict__ tb){
  __shared__ float sred[4*512];   // 8 KB
  const int t = threadIdx.x, w = t >> 6, l = t & 63;
  const int r0 = blockIdx.x * 16;
  const int lane15 = l & 15, kb = l >> 4;
  const size_t rowbase = (size_t)(r0 + lane15) * DIN;
  const int kbase = w * 1024;

  f32x4 acc0 = {0.f,0.f,0.f,0.f}, acc1 = {0.f,0.f,0.f,0.f};
  const __hip_bfloat16* at0 = At + (size_t)lane15*DIN;
  const __hip_bfloat16* at1 = At + (size_t)(16+lane15)*DIN;

  #pragma unroll 2
  for (int kt = 0; kt < 32; ++kt){
    const int k0 = kbase + kt*32 + kb*8;
    float4 xa = *(const float4*)(x  + rowbase + k0);
    float4 xc = *(const float4*)(x  + rowbase + k0 + 4);
    float4 ma = *(const float4*)(mk + rowbase + k0);
    float4 mc = *(const float4*)(mk + rowbase + k0 + 4);
    *(uint4*)(xb + rowbase + k0) = pack8(xa.x,xa.y,xa.z,xa.w,xc.x,xc.y,xc.z,xc.w);
    bf16x8 af = pack8v(xa.x*ma.x,xa.y*ma.y,xa.z*ma.z,xa.w*ma.w,
                       xc.x*mc.x,xc.y*mc.y,xc.z*mc.z,xc.w*mc.w);
    bf16x8 b0 = *(const bf16x8*)(at0 + k0);
    bf16x8 b1 = *(const bf16x8*)(at1 + k0);
    acc0 = MFMA(af, b0, acc0);
    acc1 = MFMA(af, b1, acc1);
  }

  #pragma unroll
  for (int r = 0; r < 4; ++r){
    sred[(w*64+l)*8 + r]     = acc0[r];
    sred[(w*64+l)*8 + 4 + r] = acc1[r];
  }
  __syncthreads();
  #pragma unroll
  for (int e2 = 0; e2 < 2; ++e2){
    int e  = t*2 + e2;              // e = el*8 + er
    int el = e >> 3, er = e & 7;
    float s = sred[el*8+er] + sred[512+el*8+er] + sred[1024+el*8+er] + sred[1536+el*8+er];
    int col  = (er>>2)*16 + (el & 15);
    int orow = (el>>4)*4 + (er & 3);
    tb[(size_t)(r0 + orow)*RNK + col] = __float2bfloat16(s);
  }
}

// ---------------- main GEMM: 256x256, BK=64, 8 waves, 4 single-barrier regions
// per K-tile with reads pipelined one region ahead (LDS || MFMA overlap).
// LDS per buffer b: [A|B] x [khalf] x [256][32] bf16; chunk swizzle c^=(row>>1)&3.
// Stage schedule (tile t stages t+2 into buf b=t&1): B-k0@r0, A-k0@r1, B-k1@r2,
// A-k1@r3. One vmcnt(6) per tile before r3's barrier (forces tile t+1 resident).
__global__ __launch_bounds__(512, 2) void k_main2(const __hip_bfloat16* __restrict__ xb,
                                                  const __hip_bfloat16* __restrict__ Wb,
                                                  const __hip_bfloat16* __restrict__ tb,
                                                  const __hip_bfloat16* __restrict__ Bt,
                                                  float* __restrict__ out){
  __shared__ __align__(16) __hip_bfloat16 lds[65536];   // 128 KiB
  const int tid = threadIdx.x;
  const int l  = tid & 63, w = tid >> 6;
  const int wm = w >> 2,  wn = w & 3;       // 2x4 wave grid; wave tile 128x64
  const int lr = l & 15;
  const int ch = ((l >> 4) ^ ((l >> 1) & 3)) & 3;       // swizzled 16B-chunk per lane
  const int laneA = (wm*128 + lr)*32 + ch*8;
  const int laneB = (wn*64  + lr)*32 + ch*8;
  const int g_row = tid >> 2;
  const int g_ch  = (((tid & 3) ^ ((tid >> 3) & 3))) * 8;

  // 8 XCD regions of 8m x 8n (tile grid 32m x 16n); bijective
  const int bid  = blockIdx.x;
  const int xcd  = bid & 7;
  const int idx  = bid >> 3;
  const int bm0  = (((xcd >> 1) << 3) + (idx & 7)) * 256;
  const int bn0  = (((xcd & 1) << 3) + (idx >> 3)) * 256;

  f32x4 acc[8][4];

  // ---- LoRA prologue: acc = t_frag @ Bt_frag (K=32), initializes acc ----
  {
    const __hip_bfloat16* tp = tb + (size_t)(bm0 + wm*128 + lr)*RNK + (l>>4)*8;
    const __hip_bfloat16* bp = Bt + (size_t)(bn0 + wn*64  + lr)*RNK + (l>>4)*8;
    bf16x8 tf[8], bf[4];
    #pragma unroll
    for (int m = 0; m < 8; ++m) tf[m] = *(const bf16x8*)(tp + m*16*RNK);
    #pragma unroll
    for (int n = 0; n < 4; ++n) bf[n] = *(const bf16x8*)(bp + n*16*RNK);
    const f32x4 z = {0.f,0.f,0.f,0.f};
    #pragma unroll
    for (int m = 0; m < 8; ++m)
      #pragma unroll
      for (int n = 0; n < 4; ++n)
        acc[m][n] = MFMA(tf[m], bf[n], z);
  }
  asm volatile("" ::: "memory");

  // stage one 16KB region (tile kt, ab: 0=A(xb) 1=B(Wb), khalf kh) into buffer bb
  auto STAGE = [&](int bb, int ab, int kh, int kt){
    const __hip_bfloat16* g = ab ? Wb : xb;
    const int base0 = ab ? bn0 : bm0;
    const int segb  = bb*32768 + ab*16384 + kh*8192;    // elements
    #pragma unroll
    for (int i = 0; i < 2; ++i){
      const __hip_bfloat16* src = g + (size_t)(base0 + i*128 + g_row)*DIN
                                    + kt*64 + kh*32 + g_ch;
      gload_lds16(src, (void*)&lds[segb + i*4096 + w*512]);
    }
  };

  #define ASEG(bb,kh) ((bb)*32768 + (kh)*8192)
  #define BSEG(bb,kh) ((bb)*32768 + 16384 + (kh)*8192)
  #define LDV(off) (*(const bf16x8*)&lds[(off)])

  // prologue: stage tiles 0 and 1 fully
  STAGE(0,1,0,0); STAGE(0,0,0,0); STAGE(0,1,1,0); STAGE(0,0,1,0);
  STAGE(1,1,0,1); STAGE(1,0,0,1); STAGE(1,1,1,1); STAGE(1,0,1,1);
  asm volatile("s_waitcnt vmcnt(8)" ::: "memory");      // tile0 resident
  BAR; SB0;

  bf16x8 aE[4], aO[4], bk0[4], bk1[4];
  // pre-reads for MFMA-0 of tile 0 (emulates r3 of t=-1)
  #pragma unroll
  for (int i = 0; i < 4; ++i) aE[i] = LDV(ASEG(0,0)+laneA+i*512);
  #pragma unroll
  for (int n = 0; n < 4; ++n) bk0[n] = LDV(BSEG(0,0)+laneB+n*512);

  for (int t = 0; t < NT; ++t){
    const int b = t & 1, bn = b ^ 1;

    // ---- r0: reads A-k0 m4-7 -> aO, B-k1 -> bk1; stage B-k0(t+2); MFMA-0
    BAR; SB0;
    #pragma unroll
    for (int i = 0; i < 4; ++i) aO[i] = LDV(ASEG(b,0)+laneA+2048+i*512);
    #pragma unroll
    for (int n = 0; n < 4; ++n) bk1[n] = LDV(BSEG(b,1)+laneB+n*512);
    if (t+2 < NT) STAGE(b, 1, 0, t+2);
    PRIO1;
    #pragma unroll
    for (int n = 0; n < 4; ++n){
      acc[0][n] = MFMA(aE[0], bk0[n], acc[0][n]);
      acc[1][n] = MFMA(aE[1], bk0[n], acc[1][n]);
      acc[2][n] = MFMA(aE[2], bk0[n], acc[2][n]);
      acc[3][n] = MFMA(aE[3], bk0[n], acc[3][n]);
    }
    PRIO0;

    // ---- r1: reads A-k1 m0-3 -> aE; stage A-k0(t+2); MFMA-1 (aO x bk0)
    BAR; SB0;
    #pragma unroll
    for (int i = 0; i < 4; ++i) aE[i] = LDV(ASEG(b,1)+laneA+i*512);
    if (t+2 < NT) STAGE(b, 0, 0, t+2);
    PRIO1;
    #pragma unroll
    for (int n = 0; n < 4; ++n){
      acc[4][n] = MFMA(aO[0], bk0[n], acc[4][n]);
      acc[5][n] = MFMA(aO[1], bk0[n], acc[5][n]);
      acc[6][n] = MFMA(aO[2], bk0[n], acc[6][n]);
      acc[7][n] = MFMA(aO[3], bk0[n], acc[7][n]);
    }
    PRIO0;

    // ---- r2: reads A-k1 m4-7 -> aO; stage B-k1(t+2); MFMA-2 (aE x bk1); vmcnt
    BAR; SB0;
    #pragma unroll
    for (int i = 0; i < 4; ++i) aO[i] = LDV(ASEG(b,1)+laneA+2048+i*512);
    if (t+2 < NT) STAGE(b, 1, 1, t+2);
    PRIO1;
    #pragma unroll
    for (int n = 0; n < 4; ++n){
      acc[0][n] = MFMA(aE[0], bk1[n], acc[0][n]);
      acc[1][n] = MFMA(aE[1], bk1[n], acc[1][n]);
      acc[2][n] = MFMA(aE[2], bk1[n], acc[2][n]);
      acc[3][n] = MFMA(aE[3], bk1[n], acc[3][n]);
    }
    PRIO0;
    asm volatile("s_waitcnt vmcnt(6)" ::: "memory");    // tile t+1 fully resident

    // ---- r3: reads A-k0(t+1) m0-3 -> aE, B-k0(t+1) -> bk0 (buf bn);
    //          stage A-k1(t+2); MFMA-3 (aO x bk1)
    BAR; SB0;
    if (t+1 < NT){
      #pragma unroll
      for (int i = 0; i < 4; ++i) aE[i] = LDV(ASEG(bn,0)+laneA+i*512);
      #pragma unroll
      for (int n = 0; n < 4; ++n) bk0[n] = LDV(BSEG(bn,0)+laneB+n*512);
    }
    if (t+2 < NT) STAGE(b, 0, 1, t+2);
    PRIO1;
    #pragma unroll
    for (int n = 0; n < 4; ++n){
      acc[4][n] = MFMA(aO[0], bk1[n], acc[4][n]);
      acc[5][n] = MFMA(aO[1], bk1[n], acc[5][n]);
      acc[6][n] = MFMA(aO[2], bk1[n], acc[6][n]);
      acc[7][n] = MFMA(aO[3], bk1[n], acc[7][n]);
    }
    PRIO0;
  }

  // ---- epilogue: C write (f32) ----
  const int orow = bm0 + wm*128 + (l>>4)*4;
  const int ocol = bn0 + wn*64  + (l&15);
  #pragma unroll
  for (int m = 0; m < 8; ++m)
    #pragma unroll
    for (int n = 0; n < 4; ++n)
      #pragma unroll
      for (int r = 0; r < 4; ++r)
        out[(size_t)(orow + m*16 + r)*DOUT + ocol + n*16] = acc[m][n][r];
  #undef LDV
  #undef ASEG
  #undef BSEG
}

// ---------------- fallback (ws too small): slow but correct fp32 ----------
__global__ void fb_t(const float* __restrict__ x, const float* __restrict__ mk,
                     const float* __restrict__ A, float* __restrict__ tf){
  const int m = blockIdx.x, t = threadIdx.x;
  float acc[RNK];
  #pragma unroll
  for (int r = 0; r < RNK; ++r) acc[r] = 0.f;
  for (int k = t; k < DIN; k += 256){
    float xm = x[(size_t)m*DIN + k] * mk[(size_t)m*DIN + k];
    #pragma unroll
    for (int r = 0; r < RNK; ++r) acc[r] += xm * A[(size_t)k*RNK + r];
  }
  #pragma unroll
  for (int r = 0; r < RNK; ++r){
    float v = acc[r];
    for (int o = 32; o; o >>= 1) v += __shfl_down(v, o);
    if ((t & 63) == 0) atomicAdd(&tf[(size_t)m*RNK + r], v);
  }
}

__global__ void fb_out(const float* __restrict__ x, const float* __restrict__ W,
                       const float* __restrict__ B, const float* __restrict__ tf,
                       float* __restrict__ out){
  size_t idx = (size_t)blockIdx.x*256 + threadIdx.x;
  int m = (int)(idx >> 12), n = (int)(idx & 4095);
  float acc = 0.f;
  for (int k = 0; k < DIN; ++k)
    acc += x[(size_t)m*DIN + k] * W[(size_t)n*DIN + k];
  #pragma unroll
  for (int r = 0; r < RNK; ++r)
    acc += tf[(size_t)m*RNK + r] * B[(size_t)r*DOUT + n];
  out[idx] = acc;
}

extern "C" void kernel_launch(void* const* d_in, const int* in_sizes, int n_in,
                              void* d_out, int out_size, void* d_ws, size_t ws_size,
                              hipStream_t stream) {
  const float* x  = (const float*)d_in[0];
  const float* W  = (const float*)d_in[1];
  const float* A  = (const float*)d_in[2];
  const float* B  = (const float*)d_in[3];
  const float* mk = (const float*)d_in[4];
  float* out = (float*)d_out;

  const size_t OFF_XB = 0;
  const size_t OFF_WB = OFF_XB + (size_t)MTOT*DIN*2;
  const size_t OFF_TB = OFF_WB + (size_t)DOUT*DIN*2;
  const size_t OFF_AT = OFF_TB + (size_t)MTOT*RNK*2;
  const size_t OFF_BT = OFF_AT + (size_t)RNK*DIN*2;
  const size_t NEED   = OFF_BT + (size_t)DIN*RNK*2;

  if (ws_size >= NEED){
    char* ws = (char*)d_ws;
    __hip_bfloat16* xb = (__hip_bfloat16*)(ws + OFF_XB);
    __hip_bfloat16* Wb = (__hip_bfloat16*)(ws + OFF_WB);
    __hip_bfloat16* tb = (__hip_bfloat16*)(ws + OFF_TB);
    __hip_bfloat16* At = (__hip_bfloat16*)(ws + OFF_AT);
    __hip_bfloat16* Bt = (__hip_bfloat16*)(ws + OFF_BT);

    k_conv_w <<<(DOUT*(size_t)DIN)/(256*8), 256, 0, stream>>>(W, Wb);
    k_conv_ab<<<(2*DIN*RNK)/256,            256, 0, stream>>>(A, B, At, Bt);
    k_xt     <<<MTOT/16,                    256, 0, stream>>>(x, mk, At, xb, tb);
    k_main2  <<<(MTOT/256)*(DOUT/256),      512, 0, stream>>>(xb, Wb, tb, Bt, out);
  } else {
    float* tf = (float*)d_ws;
    hipMemsetAsync(tf, 0, (size_t)MTOT*RNK*4, stream);
    fb_t  <<<MTOT, 256, 0, stream>>>(x, mk, A, tf);
    fb_out<<<((size_t)MTOT*DOUT)/256, 256, 0, stream>>>(x, W, B, tf, out);
  }
}